// Round 7
// baseline (315.387 us; speedup 1.0000x reference)
//
#include <hip/hip_runtime.h>

#define E_EDGES 1600000
#define BM 64
#define TPB 512
#define NTILES (E_EDGES / BM)   // 25000 exactly
#define GRID 512
#define WOFF 40960              // shorts reserved for weights in d_ws
#define XBF_SHORTS (100000 * 64)

typedef short s16x8 __attribute__((ext_vector_type(8)));
typedef float f32x4 __attribute__((ext_vector_type(4)));

__device__ __forceinline__ unsigned short f2bf(float f) {
    unsigned int u = __builtin_bit_cast(unsigned int, f);
    u += 0x7FFFu + ((u >> 16) & 1u);   // RNE
    return (unsigned short)(u >> 16);
}

__device__ __forceinline__ s16x8 pack8(float4 a, float4 b) {
    s16x8 r;
    r[0] = (short)f2bf(a.x); r[1] = (short)f2bf(a.y);
    r[2] = (short)f2bf(a.z); r[3] = (short)f2bf(a.w);
    r[4] = (short)f2bf(b.x); r[5] = (short)f2bf(b.y);
    r[6] = (short)f2bf(b.z); r[7] = (short)f2bf(b.w);
    return r;
}

__device__ __forceinline__ s16x8 pack8v(f32x4 a, f32x4 b) {
    s16x8 r;
    r[0] = (short)f2bf(a[0]); r[1] = (short)f2bf(a[1]);
    r[2] = (short)f2bf(a[2]); r[3] = (short)f2bf(a[3]);
    r[4] = (short)f2bf(b[0]); r[5] = (short)f2bf(b[1]);
    r[6] = (short)f2bf(b[2]); r[7] = (short)f2bf(b[3]);
    return r;
}

// d_ws layout (shorts): [0,16384) Wnnn^T [128o][128i]; [16384,24576) Wroot^T [128o][64i];
//                       [24576,40960) Wout^T [128o][128i]; [40960, +6.4M) x as bf16
__global__ void prep_w(const float* __restrict__ Wn, const float* __restrict__ Wr,
                       const float* __restrict__ Wo, unsigned short* __restrict__ wt) {
    int t = blockIdx.x * 256 + threadIdx.x;
    if (t < 16384) {
        int o = t >> 7, i = t & 127;
        wt[t] = f2bf(Wn[i * 128 + o]);
    } else if (t < 24576) {
        int q = t - 16384;
        int o = q >> 6, i = q & 63;
        wt[t] = f2bf(Wr[i * 128 + o]);
    } else if (t < 40960) {
        int q = t - 24576;
        int o = q >> 7, i = q & 127;
        wt[t] = f2bf(Wo[i * 128 + o]);
    }
}

__global__ void prep_x(const float* __restrict__ x, unsigned short* __restrict__ xb) {
    int i = blockIdx.x * 256 + threadIdx.x;    // 800000 chunks of 8 floats
    if (i < XBF_SHORTS / 8) {
        const float4* p = (const float4*)(x + (size_t)i * 8);
        *(s16x8*)(xb + (size_t)i * 8) = pack8(p[0], p[1]);
    }
}

// Swapped-operand MFMA: mfma(A = W^T frag [n][k], B = data frag [k][e]).
// C-frag: col(lane&15)=e, row((lane>>4)*4+j)=n -> 4 consecutive n per lane.
// LDS chunk-major [kq][e][8 shorts]: all reads/writes linear & bank-even.
//
// 1-barrier/tile schedule (double-buffered LDS, 2-tile pipeline). Interval i:
//   A: drain regs(tile i+1) -> pair/ea buf[(i+1)&1]
//   C: issue global loads tile i+2 -> regs; issue idx tile i+3
//   D: layer1 tile i   : reads pair/ea buf[i&1], writes hid buf[i&1]
//   E: layer2 tile i-1 : reads hid buf[(i-1)&1], NT-stores out
//   __syncthreads()
// Hazards (all have exactly 1 barrier between):
//   A(i)W pair[b^1] -> D(i+1)R pair[b^1]; D(i)R pair[b] -> A(i+1)W pair[b];
//   D(i)W hid[b] -> E(i+1)R hid[b]; E(i)R hid[b^1] -> D(i+1)W hid[b^1].
template<bool XBF>
__global__ __launch_bounds__(TPB, 4) void edge_mlp(
    const float* __restrict__ x, const unsigned short* __restrict__ xb,
    const int* __restrict__ eidx, const float* __restrict__ ea,
    const float* __restrict__ bn_g, const float* __restrict__ br_g,
    const float* __restrict__ bo_g,
    const unsigned short* __restrict__ wt, float* __restrict__ out)
{
    __shared__ unsigned short sh_pair[2][16 * 64 * 8];  // 2 x 16 KB
    __shared__ unsigned short sh_ea[2][8 * 64 * 8];     // 2 x  8 KB
    __shared__ unsigned short sh_hid[2][16 * 64 * 8];   // 2 x 16 KB  => 80 KB total

    const int tid = threadIdx.x;
    const int w   = tid >> 6;        // wave 0..7 -> n-slice w*16
    const int ln  = tid & 63;
    const int lc  = ln & 15;
    const int q   = ln >> 4;         // 0..3
    const int lk8 = q * 8;

    // gather ownership: thread owns edge-row r; pair chunks c0,c0+1; ea chunk ec
    const int r   = tid >> 3;        // 0..63
    const int c0  = (tid & 7) * 2;   // even chunk 0..14 (c0<8: src half, else dst)
    const int ihalf = (c0 < 8) ? 0 : E_EDGES;
    const int ec  = tid & 7;

    const unsigned short* Wn = wt;
    const unsigned short* Wr = wt + 16384;
    const unsigned short* Wo = wt + 24576;

    // --- pinned weight A-fragments (40 VGPR) ---
    s16x8 wn[4], wr[2], wo[4];
    const int n0 = w * 16 + lc;
    #pragma unroll
    for (int kk = 0; kk < 4; ++kk) wn[kk] = *(const s16x8*)(Wn + n0 * 128 + kk * 32 + lk8);
    #pragma unroll
    for (int kk = 0; kk < 2; ++kk) wr[kk] = *(const s16x8*)(Wr + n0 * 64 + kk * 32 + lk8);
    #pragma unroll
    for (int kk = 0; kk < 4; ++kk) wo[kk] = *(const s16x8*)(Wo + n0 * 128 + kk * 32 + lk8);

    const int nb = w * 16 + q * 4;   // lane's 4 consecutive output features
    const float4 bn4 = *(const float4*)(bn_g + nb);
    const float4 br4 = *(const float4*)(br_g + nb);
    const float4 bo4 = *(const float4*)(bo_g + nb);

    // --- pipeline regs ---
    s16x8 pr0, pr1;                  // XBF pair chunks (tile in flight)
    float4 pf0, pf1, pf2, pf3;       // fallback fp32 pair chunks
    f32x4 ef0, ef1;                  // ea 32B slice (NT loads)
    int icc;                         // idx in flight for the next C-phase

    const int t0 = blockIdx.x;
    const int T  = (NTILES - 1 - t0) / GRID + 1;   // tiles for this block (>=1)

    // ---- prologue: drain tile0 -> buf0, issue tile1 data, issue tile2 idx ----
    {
        int i0 = eidx[ihalf + t0 * BM + r];
        if constexpr (XBF) {
            const s16x8* xp = (const s16x8*)(xb + (size_t)i0 * 64 + (c0 & 7) * 8);
            s16x8 a = xp[0], b = xp[1];
            *(s16x8*)((char*)sh_pair[0] + c0 * 1024 + r * 16)       = a;
            *(s16x8*)((char*)sh_pair[0] + (c0 + 1) * 1024 + r * 16) = b;
        } else {
            const float4* xp = (const float4*)(x + (size_t)i0 * 64 + (c0 & 7) * 8);
            float4 a = xp[0], b = xp[1], c = xp[2], d = xp[3];
            *(s16x8*)((char*)sh_pair[0] + c0 * 1024 + r * 16)       = pack8(a, b);
            *(s16x8*)((char*)sh_pair[0] + (c0 + 1) * 1024 + r * 16) = pack8(c, d);
        }
        {
            const f32x4* ep = (const f32x4*)(ea + (size_t)(t0 * BM + r) * 64 + ec * 8);
            f32x4 a = __builtin_nontemporal_load(ep);
            f32x4 b = __builtin_nontemporal_load(ep + 1);
            *(s16x8*)((char*)sh_ea[0] + ec * 1024 + r * 16) = pack8v(a, b);
        }
        // issue tile1 data
        int t1 = (T > 1) ? t0 + GRID : t0;
        int i1 = eidx[ihalf + t1 * BM + r];
        if constexpr (XBF) {
            const s16x8* xp = (const s16x8*)(xb + (size_t)i1 * 64 + (c0 & 7) * 8);
            pr0 = xp[0]; pr1 = xp[1];
        } else {
            const float4* xp = (const float4*)(x + (size_t)i1 * 64 + (c0 & 7) * 8);
            pf0 = xp[0]; pf1 = xp[1]; pf2 = xp[2]; pf3 = xp[3];
        }
        {
            const f32x4* ep = (const f32x4*)(ea + (size_t)(t1 * BM + r) * 64 + ec * 8);
            ef0 = __builtin_nontemporal_load(ep);
            ef1 = __builtin_nontemporal_load(ep + 1);
        }
        // issue tile2 idx
        int t2 = (T > 2) ? t0 + 2 * GRID : t0;
        icc = eidx[ihalf + t2 * BM + r];
        __syncthreads();
    }

    for (int i = 0; i <= T; ++i) {
        const int bD = i & 1, bA = bD ^ 1;

        // --- A: drain regs (tile i+1) -> buf[bA] ---
        if (i + 1 < T) {
            if constexpr (XBF) {
                *(s16x8*)((char*)sh_pair[bA] + c0 * 1024 + r * 16)       = pr0;
                *(s16x8*)((char*)sh_pair[bA] + (c0 + 1) * 1024 + r * 16) = pr1;
            } else {
                *(s16x8*)((char*)sh_pair[bA] + c0 * 1024 + r * 16)       = pack8(pf0, pf1);
                *(s16x8*)((char*)sh_pair[bA] + (c0 + 1) * 1024 + r * 16) = pack8(pf2, pf3);
            }
            *(s16x8*)((char*)sh_ea[bA] + ec * 1024 + r * 16) = pack8v(ef0, ef1);
        }

        // --- C: issue tile i+2 data (idx = icc), then idx for tile i+3 ---
        if (i + 2 < T) {
            const int tc = t0 + (i + 2) * GRID;
            if constexpr (XBF) {
                const s16x8* xp = (const s16x8*)(xb + (size_t)icc * 64 + (c0 & 7) * 8);
                pr0 = xp[0]; pr1 = xp[1];
            } else {
                const float4* xp = (const float4*)(x + (size_t)icc * 64 + (c0 & 7) * 8);
                pf0 = xp[0]; pf1 = xp[1]; pf2 = xp[2]; pf3 = xp[3];
            }
            {
                const f32x4* ep = (const f32x4*)(ea + (size_t)(tc * BM + r) * 64 + ec * 8);
                ef0 = __builtin_nontemporal_load(ep);
                ef1 = __builtin_nontemporal_load(ep + 1);
            }
            int t3 = (i + 3 < T) ? t0 + (i + 3) * GRID : t0;
            icc = eidx[ihalf + t3 * BM + r];
        }

        // --- D: layer 1, tile i: pair/ea buf[bD] -> hid buf[bD] ---
        if (i < T) {
            #pragma unroll
            for (int m = 0; m < 4; ++m) {
                const int e = m * 16 + lc;
                f32x4 a1 = {0.f, 0.f, 0.f, 0.f};
                f32x4 a2 = {0.f, 0.f, 0.f, 0.f};
                #pragma unroll
                for (int kk = 0; kk < 4; ++kk) {
                    s16x8 g = *(const s16x8*)((const char*)sh_pair[bD] + (kk * 4 + q) * 1024 + e * 16);
                    a1 = __builtin_amdgcn_mfma_f32_16x16x32_bf16(wn[kk], g, a1, 0, 0, 0);
                }
                #pragma unroll
                for (int kk = 0; kk < 2; ++kk) {
                    s16x8 g = *(const s16x8*)((const char*)sh_ea[bD] + (kk * 4 + q) * 1024 + e * 16);
                    a2 = __builtin_amdgcn_mfma_f32_16x16x32_bf16(wr[kk], g, a2, 0, 0, 0);
                }
                unsigned short h0 = f2bf(fmaxf(a1[0] + bn4.x, 0.f) + fmaxf(a2[0] + br4.x, 0.f));
                unsigned short h1 = f2bf(fmaxf(a1[1] + bn4.y, 0.f) + fmaxf(a2[1] + br4.y, 0.f));
                unsigned short h2 = f2bf(fmaxf(a1[2] + bn4.z, 0.f) + fmaxf(a2[2] + br4.z, 0.f));
                unsigned short h3 = f2bf(fmaxf(a1[3] + bn4.w, 0.f) + fmaxf(a2[3] + br4.w, 0.f));
                uint2 hv;
                hv.x = (unsigned)h0 | ((unsigned)h1 << 16);
                hv.y = (unsigned)h2 | ((unsigned)h3 << 16);
                *(uint2*)((char*)sh_hid[bD] + (w * 2 + (q >> 1)) * 1024 + e * 16 + (q & 1) * 8) = hv;
            }
        }

        // --- E: layer 2, tile i-1: hid buf[bA] -> out (NT stores) ---
        if (i >= 1) {
            const int base = (t0 + (i - 1) * GRID) * BM;
            #pragma unroll
            for (int m = 0; m < 4; ++m) {
                const int e = m * 16 + lc;
                f32x4 a3 = {0.f, 0.f, 0.f, 0.f};
                #pragma unroll
                for (int kk = 0; kk < 4; ++kk) {
                    s16x8 g = *(const s16x8*)((const char*)sh_hid[bA] + (kk * 4 + q) * 1024 + e * 16);
                    a3 = __builtin_amdgcn_mfma_f32_16x16x32_bf16(wo[kk], g, a3, 0, 0, 0);
                }
                f32x4 o;
                o[0] = fmaxf(a3[0] + bo4.x, 0.f);
                o[1] = fmaxf(a3[1] + bo4.y, 0.f);
                o[2] = fmaxf(a3[2] + bo4.z, 0.f);
                o[3] = fmaxf(a3[3] + bo4.w, 0.f);
                __builtin_nontemporal_store(o, (f32x4*)(out + (size_t)(base + e) * 128 + nb));
            }
        }

        if (i < T) __syncthreads();
    }
}

extern "C" void kernel_launch(void* const* d_in, const int* in_sizes, int n_in,
                              void* d_out, int out_size, void* d_ws, size_t ws_size,
                              hipStream_t stream) {
    const float* x   = (const float*)d_in[0];
    const int*   ei  = (const int*)d_in[1];
    const float* ea  = (const float*)d_in[2];
    const float* Wn  = (const float*)d_in[3];
    const float* bn  = (const float*)d_in[4];
    const float* Wr  = (const float*)d_in[5];
    const float* br  = (const float*)d_in[6];
    const float* Wo  = (const float*)d_in[7];
    const float* bo  = (const float*)d_in[8];
    float* out = (float*)d_out;
    unsigned short* wt = (unsigned short*)d_ws;

    const bool xbf = ws_size >= (size_t)(WOFF + XBF_SHORTS) * sizeof(unsigned short);

    prep_w<<<160, 256, 0, stream>>>(Wn, Wr, Wo, wt);
    if (xbf) {
        prep_x<<<XBF_SHORTS / 8 / 256, 256, 0, stream>>>(x, wt + WOFF);
        edge_mlp<true><<<GRID, TPB, 0, stream>>>(x, wt + WOFF, ei, ea, bn, br, bo, wt, out);
    } else {
        edge_mlp<false><<<GRID, TPB, 0, stream>>>(x, nullptr, ei, ea, bn, br, bo, wt, out);
    }
}

// Round 8
// 294.834 us; speedup vs baseline: 1.0697x; 1.0697x over previous
//
#include <hip/hip_runtime.h>

#define E_EDGES 1600000
#define BM 64
#define TPB 512
#define NTILES (E_EDGES / BM)   // 25000 exactly
#define GRID 1024               // 4 blocks/CU: LDS 4x40KB = 160KB exactly, VGPR 64 -> 8 waves/SIMD
#define WOFF 40960              // shorts reserved for weights in d_ws
#define XBF_SHORTS (100000 * 64)

typedef short s16x8 __attribute__((ext_vector_type(8)));
typedef float f32x4 __attribute__((ext_vector_type(4)));

__device__ __forceinline__ unsigned short f2bf(float f) {
    unsigned int u = __builtin_bit_cast(unsigned int, f);
    u += 0x7FFFu + ((u >> 16) & 1u);   // RNE
    return (unsigned short)(u >> 16);
}

__device__ __forceinline__ s16x8 pack8(float4 a, float4 b) {
    s16x8 r;
    r[0] = (short)f2bf(a.x); r[1] = (short)f2bf(a.y);
    r[2] = (short)f2bf(a.z); r[3] = (short)f2bf(a.w);
    r[4] = (short)f2bf(b.x); r[5] = (short)f2bf(b.y);
    r[6] = (short)f2bf(b.z); r[7] = (short)f2bf(b.w);
    return r;
}

// d_ws layout (shorts): [0,16384) Wnnn^T [128o][128i]; [16384,24576) Wroot^T [128o][64i];
//                       [24576,40960) Wout^T [128o][128i]; [40960, +6.4M) x as bf16
__global__ void prep_w(const float* __restrict__ Wn, const float* __restrict__ Wr,
                       const float* __restrict__ Wo, unsigned short* __restrict__ wt) {
    int t = blockIdx.x * 256 + threadIdx.x;
    if (t < 16384) {
        int o = t >> 7, i = t & 127;
        wt[t] = f2bf(Wn[i * 128 + o]);
    } else if (t < 24576) {
        int q = t - 16384;
        int o = q >> 6, i = q & 63;
        wt[t] = f2bf(Wr[i * 128 + o]);
    } else if (t < 40960) {
        int q = t - 24576;
        int o = q >> 7, i = q & 127;
        wt[t] = f2bf(Wo[i * 128 + o]);
    }
}

__global__ void prep_x(const float* __restrict__ x, unsigned short* __restrict__ xb) {
    int i = blockIdx.x * 256 + threadIdx.x;    // 800000 chunks of 8 floats
    if (i < XBF_SHORTS / 8) {
        const float4* p = (const float4*)(x + (size_t)i * 8);
        *(s16x8*)(xb + (size_t)i * 8) = pack8(p[0], p[1]);
    }
}

// Swapped-operand MFMA: mfma(A = W^T frag [n][k], B = data frag [k][e]).
// C-frag: col(lane&15)=e, row((lane>>4)*4+j)=n -> 4 consecutive n per lane ->
// b64 hid writes, dwordx4 out stores.
// LDS tiles are chunk-major [kq][e][8 shorts]: B-frag read for (kk,q,e) is the
// 16B at (kk*4+q)*1024 + e*16 -> linear, bank-even, no swizzle needed.
template<bool XBF>
__global__ __launch_bounds__(TPB, 4) void edge_mlp(
    const float* __restrict__ x, const unsigned short* __restrict__ xb,
    const int* __restrict__ eidx, const float* __restrict__ ea,
    const float* __restrict__ bn_g, const float* __restrict__ br_g,
    const float* __restrict__ bo_g,
    const unsigned short* __restrict__ wt, float* __restrict__ out)
{
    __shared__ unsigned short sh_pair[16 * 64 * 8];  // [kq][e][8], 16 KB
    __shared__ unsigned short sh_ea[8 * 64 * 8];     // [kq][e][8],  8 KB
    __shared__ unsigned short sh_hid[16 * 64 * 8];   // [kq][e][8], 16 KB

    const int tid = threadIdx.x;
    const int w   = tid >> 6;        // wave 0..7 -> n-slice w*16
    const int ln  = tid & 63;
    const int lc  = ln & 15;
    const int q   = ln >> 4;         // 0..3
    const int lk8 = q * 8;

    // gather ownership: thread owns edge-row r; pair chunks c0,c0+1; ea chunk ec
    const int r   = tid >> 3;        // 0..63
    const int c0  = (tid & 7) * 2;   // even chunk 0..14 (c0<8: src half, else dst)
    const int ihalf = (c0 < 8) ? 0 : E_EDGES;
    const int ec  = tid & 7;

    const unsigned short* Wn = wt;
    const unsigned short* Wr = wt + 16384;
    const unsigned short* Wo = wt + 24576;

    // --- pinned weight A-fragments (40 VGPR) ---
    s16x8 wn[4], wr[2], wo[4];
    const int n0 = w * 16 + lc;
    #pragma unroll
    for (int kk = 0; kk < 4; ++kk) wn[kk] = *(const s16x8*)(Wn + n0 * 128 + kk * 32 + lk8);
    #pragma unroll
    for (int kk = 0; kk < 2; ++kk) wr[kk] = *(const s16x8*)(Wr + n0 * 64 + kk * 32 + lk8);
    #pragma unroll
    for (int kk = 0; kk < 4; ++kk) wo[kk] = *(const s16x8*)(Wo + n0 * 128 + kk * 32 + lk8);

    const int nb = w * 16 + q * 4;   // lane's 4 consecutive output features
    const float4 bn4 = *(const float4*)(bn_g + nb);
    const float4 br4 = *(const float4*)(br_g + nb);
    const float4 bo4 = *(const float4*)(bo_g + nb);

    // --- pipeline regs: tile t+1 data, tile t+2 index ---
    s16x8 pr0, pr1;                  // XBF pair chunks
    float4 pf0, pf1, pf2, pf3;       // fallback fp32 pair chunks
    float4 ef0, ef1;                 // ea 32B slice
    int ic, ic_n;

    int tile = blockIdx.x;
    if (tile >= NTILES) return;

    // prologue: tile-0 data, tile-1 index
    ic = eidx[ihalf + tile * BM + r];
    if constexpr (XBF) {
        const s16x8* xp = (const s16x8*)(xb + (size_t)ic * 64 + (c0 & 7) * 8);
        pr0 = xp[0]; pr1 = xp[1];
    } else {
        const float4* xp = (const float4*)(x + (size_t)ic * 64 + (c0 & 7) * 8);
        pf0 = xp[0]; pf1 = xp[1]; pf2 = xp[2]; pf3 = xp[3];
    }
    {
        const float4* ep = (const float4*)(ea + (size_t)(tile * BM + r) * 64 + ec * 8);
        ef0 = ep[0]; ef1 = ep[1];
    }
    {
        int t1 = (tile + GRID < NTILES) ? tile + GRID : tile;
        ic_n = eidx[ihalf + t1 * BM + r];
    }

    for (; tile < NTILES; tile += GRID) {
        const int base = tile * BM;
        const int tn  = (tile + GRID < NTILES) ? tile + GRID : tile;
        const int tnn = (tn + GRID < NTILES) ? tn + GRID : tn;

        // --- A: drain prefetch -> LDS (chunk-major) ---
        if constexpr (XBF) {
            *(s16x8*)((char*)sh_pair + c0 * 1024 + r * 16)       = pr0;
            *(s16x8*)((char*)sh_pair + (c0 + 1) * 1024 + r * 16) = pr1;
        } else {
            *(s16x8*)((char*)sh_pair + c0 * 1024 + r * 16)       = pack8(pf0, pf1);
            *(s16x8*)((char*)sh_pair + (c0 + 1) * 1024 + r * 16) = pack8(pf2, pf3);
        }
        *(s16x8*)((char*)sh_ea + ec * 1024 + r * 16) = pack8(ef0, ef1);

        // --- C: issue tile t+1 loads (cover: D + barrier + E) ---
        ic = ic_n;
        if constexpr (XBF) {
            const s16x8* xp = (const s16x8*)(xb + (size_t)ic * 64 + (c0 & 7) * 8);
            pr0 = xp[0]; pr1 = xp[1];
        } else {
            const float4* xp = (const float4*)(x + (size_t)ic * 64 + (c0 & 7) * 8);
            pf0 = xp[0]; pf1 = xp[1]; pf2 = xp[2]; pf3 = xp[3];
        }
        {
            const float4* ep = (const float4*)(ea + (size_t)(tn * BM + r) * 64 + ec * 8);
            ef0 = ep[0]; ef1 = ep[1];
        }
        ic_n = eidx[ihalf + tnn * BM + r];   // tile t+2 index (full-tile cover)

        __syncthreads();   // barrier1: LDS pair/ea ready; hid E(t-1) reads done

        // --- D: layer 1 -> sh_hid ---
        #pragma unroll
        for (int m = 0; m < 4; ++m) {
            const int e = m * 16 + lc;
            f32x4 a1 = {0.f, 0.f, 0.f, 0.f};
            f32x4 a2 = {0.f, 0.f, 0.f, 0.f};
            #pragma unroll
            for (int kk = 0; kk < 4; ++kk) {
                s16x8 g = *(const s16x8*)((const char*)sh_pair + (kk * 4 + q) * 1024 + e * 16);
                a1 = __builtin_amdgcn_mfma_f32_16x16x32_bf16(wn[kk], g, a1, 0, 0, 0);
            }
            #pragma unroll
            for (int kk = 0; kk < 2; ++kk) {
                s16x8 g = *(const s16x8*)((const char*)sh_ea + (kk * 4 + q) * 1024 + e * 16);
                a2 = __builtin_amdgcn_mfma_f32_16x16x32_bf16(wr[kk], g, a2, 0, 0, 0);
            }
            unsigned short h0 = f2bf(fmaxf(a1[0] + bn4.x, 0.f) + fmaxf(a2[0] + br4.x, 0.f));
            unsigned short h1 = f2bf(fmaxf(a1[1] + bn4.y, 0.f) + fmaxf(a2[1] + br4.y, 0.f));
            unsigned short h2 = f2bf(fmaxf(a1[2] + bn4.z, 0.f) + fmaxf(a2[2] + br4.z, 0.f));
            unsigned short h3 = f2bf(fmaxf(a1[3] + bn4.w, 0.f) + fmaxf(a2[3] + br4.w, 0.f));
            uint2 hv;
            hv.x = (unsigned)h0 | ((unsigned)h1 << 16);
            hv.y = (unsigned)h2 | ((unsigned)h3 << 16);
            // hid chunk = (w*16+q*4)/8 = w*2 + (q>>1); byte within chunk-row = (q&1)*8
            *(uint2*)((char*)sh_hid + (w * 2 + (q >> 1)) * 1024 + e * 16 + (q & 1) * 8) = hv;
        }
        __syncthreads();   // barrier2: hid ready; pair/ea reads done before A(t+1)

        // --- E: layer 2 -> out ---
        #pragma unroll
        for (int m = 0; m < 4; ++m) {
            const int e = m * 16 + lc;
            f32x4 a3 = {0.f, 0.f, 0.f, 0.f};
            #pragma unroll
            for (int kk = 0; kk < 4; ++kk) {
                s16x8 g = *(const s16x8*)((const char*)sh_hid + (kk * 4 + q) * 1024 + e * 16);
                a3 = __builtin_amdgcn_mfma_f32_16x16x32_bf16(wo[kk], g, a3, 0, 0, 0);
            }
            float4 o;
            o.x = fmaxf(a3[0] + bo4.x, 0.f);
            o.y = fmaxf(a3[1] + bo4.y, 0.f);
            o.z = fmaxf(a3[2] + bo4.z, 0.f);
            o.w = fmaxf(a3[3] + bo4.w, 0.f);
            *(float4*)(out + (size_t)(base + e) * 128 + nb) = o;
        }
    }
}

extern "C" void kernel_launch(void* const* d_in, const int* in_sizes, int n_in,
                              void* d_out, int out_size, void* d_ws, size_t ws_size,
                              hipStream_t stream) {
    const float* x   = (const float*)d_in[0];
    const int*   ei  = (const int*)d_in[1];
    const float* ea  = (const float*)d_in[2];
    const float* Wn  = (const float*)d_in[3];
    const float* bn  = (const float*)d_in[4];
    const float* Wr  = (const float*)d_in[5];
    const float* br  = (const float*)d_in[6];
    const float* Wo  = (const float*)d_in[7];
    const float* bo  = (const float*)d_in[8];
    float* out = (float*)d_out;
    unsigned short* wt = (unsigned short*)d_ws;

    const bool xbf = ws_size >= (size_t)(WOFF + XBF_SHORTS) * sizeof(unsigned short);

    prep_w<<<160, 256, 0, stream>>>(Wn, Wr, Wo, wt);
    if (xbf) {
        prep_x<<<XBF_SHORTS / 8 / 256, 256, 0, stream>>>(x, wt + WOFF);
        edge_mlp<true><<<GRID, TPB, 0, stream>>>(x, wt + WOFF, ei, ea, bn, br, bo, wt, out);
    } else {
        edge_mlp<false><<<GRID, TPB, 0, stream>>>(x, nullptr, ei, ea, bn, br, bo, wt, out);
    }
}